// Round 8
// baseline (892.483 us; speedup 1.0000x reference)
//
#include <hip/hip_runtime.h>
#include <math.h>

// Problem constants
#define BB 8
#define CC 64
#define TT 512
#define FF 256

typedef float floatx4 __attribute__((ext_vector_type(4)));

constexpr int TOFF = BB * FF;                       // 2048
constexpr int COFF = BB * FF + BB * TT;             // 6144
constexpr int NSUM = BB * FF + BB * TT + BB * CC;   // 6656 floats

// ws layout (floats)
constexpr long PF_OFF  = 0;                         // Pfreq [4096][256]
constexpr long PT_OFF  = PF_OFF + 4096L * 256;      // Ptime [4096][64]
constexpr long PC_OFF  = PT_OFF + 4096L * 64;       // Pch   [4096]
constexpr long G_OFF   = PC_OFF + 4096;             // gates [NSUM]
constexpr long CNT_OFF = G_OFF + NSUM;              // 2 ints

struct PoolShm { float tr[16][257]; float fr[256]; float cw[4]; };  // 17.5 KB
struct GateShm { float s[512]; float h[512]; };                     //  4 KB
union  Shm { PoolShm p; GateShm g; };

// ---------------------------------------------------------------------------
// Device-scope spin barrier (non-cooperative). SAFE because the whole grid
// (1024 blocks @ 4/CU needed) is co-resident with 2x capacity margin
// (LDS 17.5KB -> 9/CU, launch_bounds(256,4) -> VGPR<=128). Standard
// release(threadfence)+atomicAdd / acquire(spin+threadfence) pattern.
// ---------------------------------------------------------------------------
__device__ __forceinline__ void sync_spin(int* cnt, int target, bool add) {
    __syncthreads();                       // block writes drained (vmcnt 0)
    if (threadIdx.x == 0) {
        if (add) {
            __threadfence();               // release: publish our stores
            atomicAdd(cnt, 1);
        }
        while (__hip_atomic_load(cnt, __ATOMIC_ACQUIRE,
                                 __HIP_MEMORY_SCOPE_AGENT) < target)
            __builtin_amdgcn_s_sleep(10);
        __threadfence();                   // acquire: see others' stores
    }
    __syncthreads();
}

// ---------------------------------------------------------------------------
// Pool body (R7-verified math): one contiguous 64KB chunk (64 rows of F=256),
// register-only inner loop, one-time cross-lane epilogue, partials via plain
// stores. Temporal loads fill L3 so apply re-reads hit L3 (R6: ~94% hits).
// ---------------------------------------------------------------------------
__device__ __forceinline__ void pool_body(const floatx4* __restrict__ x4,
                                          float* __restrict__ pf,
                                          float* __restrict__ pt,
                                          float* __restrict__ pc,
                                          PoolShm& p, int chunk,
                                          int tid, int lane, int wid) {
    const long base = (long)chunk * 4096 + wid * 1024 + lane;

    float a0 = 0.f, a1 = 0.f, a2 = 0.f, a3 = 0.f;    // freq partials
    float ach[16];                                   // row sums (time)
    #pragma unroll
    for (int k = 0; k < 16; ++k) {
        floatx4 d = x4[base + k * 64];               // temporal: fill L3
        a0 += d.x; a1 += d.y; a2 += d.z; a3 += d.w;
        ach[k] = (d.x + d.y) + (d.z + d.w);
    }
    float csum = 0.f;
    #pragma unroll
    for (int k = 0; k < 16; ++k) csum += ach[k];
    #pragma unroll
    for (int o = 32; o > 0; o >>= 1) csum += __shfl_xor(csum, o, 64);

    p.fr[tid] = 0.f;
    #pragma unroll
    for (int k = 0; k < 16; ++k) p.tr[k][tid] = ach[k];
    if (lane == 0) p.cw[wid] = csum;
    __syncthreads();

    atomicAdd(&p.fr[4 * lane + 0], a0);
    atomicAdd(&p.fr[4 * lane + 1], a1);
    atomicAdd(&p.fr[4 * lane + 2], a2);
    atomicAdd(&p.fr[4 * lane + 3], a3);

    {   // time: row s of chunk summed by 4 threads (q), then 2 shuffles
        const int s = tid >> 2, q = tid & 3;
        float v = 0.f;
        #pragma unroll
        for (int j = 0; j < 16; ++j)
            v += p.tr[s & 15][(s >> 4) * 64 + q * 16 + j];
        v += __shfl_xor(v, 1, 64);
        v += __shfl_xor(v, 2, 64);
        if (q == 0) pt[chunk * 64 + s] = v;
    }
    __syncthreads();

    pf[chunk * 256 + tid] = p.fr[tid];
    if (tid == 0) pc[chunk] = (p.cw[0] + p.cw[1]) + (p.cw[2] + p.cw[3]);
}

// ---------------------------------------------------------------------------
// Gate body, 256 threads, one (g,b) unit per block (24 blocks).
// ---------------------------------------------------------------------------
__device__ __forceinline__ void gate_body(
    const float* __restrict__ w1f, const float* __restrict__ w2f,
    const float* __restrict__ w1t, const float* __restrict__ w2t,
    const float* __restrict__ w1c, const float* __restrict__ w2c,
    const float* __restrict__ pf, const float* __restrict__ pt,
    const float* __restrict__ pc, float* __restrict__ gates,
    GateShm& gs, int bid, int tid) {
    const int g = bid >> 3;
    const int b = bid & 7;
    int dim; const float *w1, *w2; float* gout; float inv;
    if (g == 0) { dim = FF; w1 = w1f; w2 = w2f; gout = gates + b * FF;
                  inv = 1.f / (float)(CC * TT); }
    else if (g == 1) { dim = TT; w1 = w1t; w2 = w2t; gout = gates + TOFF + b * TT;
                  inv = 1.f / (float)(CC * FF); }
    else { dim = CC; w1 = w1c; w2 = w2c; gout = gates + COFF + b * CC;
                  inv = 1.f / (float)(TT * FF); }

    // ---- reduce partials into gs.s[0..dim) ----
    if (g == 0) {
        // vectorized: wave w covers chunks w,w+4,...; lane l reads floatx4 @4l
        const int l = tid & 63, w = tid >> 6;
        floatx4 acc = {0.f, 0.f, 0.f, 0.f};
        #pragma unroll 8
        for (int ch = w; ch < 512; ch += 4)
            acc += ((const floatx4*)(pf + (long)(b * 512 + ch) * 256))[l];
        gs.s[tid] = 0.f;
        __syncthreads();
        atomicAdd(&gs.s[4 * l + 0], acc.x);
        atomicAdd(&gs.s[4 * l + 1], acc.y);
        atomicAdd(&gs.s[4 * l + 2], acc.z);
        atomicAdd(&gs.s[4 * l + 3], acc.w);
        __syncthreads();
        gs.s[tid] *= inv;
    } else if (g == 1) {
        for (int t2 = tid; t2 < TT; t2 += 256) {
            float acc = 0.f;
            const float* __restrict__ p =
                pt + (long)(b * 512 + (t2 >> 6)) * 64 + (t2 & 63);
            #pragma unroll 8
            for (int c = 0; c < 64; ++c) acc += p[(long)c * 8 * 64];
            gs.s[t2] = acc * inv;
        }
    } else {
        if (tid < CC) {
            float acc = 0.f;
            #pragma unroll
            for (int j = 0; j < 8; ++j) acc += pc[b * 512 + tid * 8 + j];
            gs.s[tid] = acc * inv;
        }
    }
    __syncthreads();

    for (int row = tid; row < dim; row += 256) {     // layer 1: relu
        const floatx4* __restrict__ wr = (const floatx4*)(w1 + (long)row * dim);
        const floatx4* __restrict__ sv = (const floatx4*)gs.s;
        float c0 = 0.f, c1 = 0.f, c2 = 0.f, c3 = 0.f;
        for (int j = 0; j < dim / 4; ++j) {
            floatx4 w = wr[j]; floatx4 sj = sv[j];
            c0 += w.x * sj.x; c1 += w.y * sj.y; c2 += w.z * sj.z; c3 += w.w * sj.w;
        }
        gs.h[row] = fmaxf((c0 + c1) + (c2 + c3), 0.f);
    }
    __syncthreads();
    for (int row = tid; row < dim; row += 256) {     // layer 2: sigmoid
        const floatx4* __restrict__ wr = (const floatx4*)(w2 + (long)row * dim);
        const floatx4* __restrict__ hv = (const floatx4*)gs.h;
        float c0 = 0.f, c1 = 0.f, c2 = 0.f, c3 = 0.f;
        for (int j = 0; j < dim / 4; ++j) {
            floatx4 w = wr[j]; floatx4 hj = hv[j];
            c0 += w.x * hj.x; c1 += w.y * hj.y; c2 += w.z * hj.z; c3 += w.w * hj.w;
        }
        gout[row] = 1.f / (1.f + expf(-((c0 + c1) + (c2 + c3))));
    }
}

// ---------------------------------------------------------------------------
// Fused kernel: pool -> spin-sync -> gates(24 blocks) -> spin-sync -> apply.
// 1024 blocks x 256 threads, all co-resident (2x occupancy margin).
// ---------------------------------------------------------------------------
__global__ __launch_bounds__(256, 4) void se_spin_k(
    const float* __restrict__ x,
    const float* __restrict__ w1f, const float* __restrict__ w2f,
    const float* __restrict__ w1t, const float* __restrict__ w2t,
    const float* __restrict__ w1c, const float* __restrict__ w2c,
    float* __restrict__ ws_f, int* __restrict__ cnt,
    float* __restrict__ out)
{
    __shared__ Shm u;
    const int tid  = threadIdx.x;
    const int lane = tid & 63;
    const int wid  = tid >> 6;
    const int bid  = blockIdx.x;
    const floatx4* __restrict__ x4 = (const floatx4*)x;

    float* pf    = ws_f + PF_OFF;
    float* pt    = ws_f + PT_OFF;
    float* pc    = ws_f + PC_OFF;
    float* gates = ws_f + G_OFF;

    // ---- Phase 1: pool (4 chunks per block, ascending => L3 full of x) ----
    for (int rep = 0; rep < 4; ++rep)
        pool_body(x4, pf, pt, pc, u.p, rep * 1024 + bid, tid, lane, wid);

    sync_spin(&cnt[0], 1024, true);

    // ---- Phase 2: gates (24 blocks; others wait) ----
    if (bid < 24)
        gate_body(w1f, w2f, w1t, w2t, w1c, w2c, pf, pt, pc, gates, u.g,
                  bid, tid);
    sync_spin(&cnt[1], 24, bid < 24);

    // ---- Phase 3: apply, descending (chases pool's MRU; R6: ~94% L3 hit) --
    floatx4* __restrict__ o4 = (floatx4*)out;
    const long base3 = (long)bid * 256 + tid;        // < 2^18
    const int f4  = (int)(base3 & 63);
    const int t   = (int)((base3 >> 6) & (TT - 1));
    const int clo = (int)((base3 >> 15) & 7);
    #pragma unroll 8
    for (int k = 63; k >= 0; --k) {
        const int b = k >> 3;
        const int c = ((k & 7) << 3) | clo;
        const floatx4 fm = ((const floatx4*)(gates + b * FF))[f4];
        const float gadd = gates[TOFF + b * TT + t]
                         + gates[COFF + b * CC + c] + 1.0f;
        const long v = base3 + ((long)k << 18);
        floatx4 d = x4[v];                           // mostly L3 hits
        floatx4 o = d * (fm + gadd);
        __builtin_nontemporal_store(o, &o4[v]);      // don't evict x
    }
}

__global__ void zero_cnt_k(int* __restrict__ cnt) {
    if (threadIdx.x < 2) cnt[threadIdx.x] = 0;
}

extern "C" void kernel_launch(void* const* d_in, const int* in_sizes, int n_in,
                              void* d_out, int out_size, void* d_ws, size_t ws_size,
                              hipStream_t stream) {
    const float* x   = (const float*)d_in[0];
    const float* w1f = (const float*)d_in[1];
    const float* w2f = (const float*)d_in[2];
    const float* w1t = (const float*)d_in[3];
    const float* w2t = (const float*)d_in[4];
    const float* w1c = (const float*)d_in[5];
    const float* w2c = (const float*)d_in[6];
    float* out  = (float*)d_out;
    float* ws_f = (float*)d_ws;
    int*   cnt  = (int*)(ws_f + CNT_OFF);

    zero_cnt_k<<<1, 64, 0, stream>>>(cnt);
    se_spin_k<<<1024, 256, 0, stream>>>(x, w1f, w2f, w1t, w2t, w1c, w2c,
                                        ws_f, cnt, out);
}

// Round 9
// 330.745 us; speedup vs baseline: 2.6984x; 2.6984x over previous
//
#include <hip/hip_runtime.h>
#include <math.h>

// Problem constants
#define BB 8
#define CC 64
#define TT 512
#define FF 256

typedef float floatx4 __attribute__((ext_vector_type(4)));

constexpr int TOFF = BB * FF;                       // 2048
constexpr int COFF = BB * FF + BB * TT;             // 6144
constexpr int NSUM = BB * FF + BB * TT + BB * CC;   // 6656 floats

// ws layout (floats)
constexpr long PF_OFF = 0;                          // Pfreq [4096][256]
constexpr long PT_OFF = PF_OFF + 4096L * 256;       // Ptime [4096][64]
constexpr long PC_OFF = PT_OFF + 4096L * 64;        // Pch   [4096]
constexpr long G_OFF  = PC_OFF + 4096;              // gates [NSUM]

// ---------------------------------------------------------------------------
// EXPERIMENT ROUND (R9): identical kernels to R7; pool_k and apply_k are each
// launched TWICE (idempotent: same partials / same output rewritten).
//   R9_dur - R7_dur = pool_hot + apply_hot + 2 node boundaries
// This decomposes R7's 204us into {pool+apply} vs {gate+boundaries}.
// ---------------------------------------------------------------------------

__global__ __launch_bounds__(256) void pool_k(const float* __restrict__ x,
                                              float* __restrict__ pf,
                                              float* __restrict__ pt,
                                              float* __restrict__ pc) {
    __shared__ float tr[16][257];
    __shared__ float fr[256];
    __shared__ float cw[4];
    const int tid  = threadIdx.x;
    const int lane = tid & 63;
    const int wid  = tid >> 6;
    const int chunk = blockIdx.x;                    // 0..4095

    const floatx4* __restrict__ x4 = (const floatx4*)x;
    const long base = (long)chunk * 4096 + wid * 1024 + lane;

    float a0 = 0.f, a1 = 0.f, a2 = 0.f, a3 = 0.f;    // freq partials
    float ach[16];                                   // row sums (time)
    #pragma unroll
    for (int k = 0; k < 16; ++k) {
        floatx4 d = x4[base + k * 64];               // temporal: fill L3
        a0 += d.x; a1 += d.y; a2 += d.z; a3 += d.w;
        ach[k] = (d.x + d.y) + (d.z + d.w);
    }
    float csum = 0.f;
    #pragma unroll
    for (int k = 0; k < 16; ++k) csum += ach[k];
    #pragma unroll
    for (int o = 32; o > 0; o >>= 1) csum += __shfl_xor(csum, o, 64);

    fr[tid] = 0.f;
    #pragma unroll
    for (int k = 0; k < 16; ++k) tr[k][tid] = ach[k];
    if (lane == 0) cw[wid] = csum;
    __syncthreads();

    atomicAdd(&fr[4 * lane + 0], a0);
    atomicAdd(&fr[4 * lane + 1], a1);
    atomicAdd(&fr[4 * lane + 2], a2);
    atomicAdd(&fr[4 * lane + 3], a3);

    {   // time: row s of chunk summed by 4 threads (q), then 2 shuffles
        const int s = tid >> 2, q = tid & 3;
        float v = 0.f;
        #pragma unroll
        for (int j = 0; j < 16; ++j)
            v += tr[s & 15][(s >> 4) * 64 + q * 16 + j];
        v += __shfl_xor(v, 1, 64);
        v += __shfl_xor(v, 2, 64);
        if (q == 0) pt[chunk * 64 + s] = v;          // plain store
    }
    __syncthreads();

    pf[chunk * 256 + tid] = fr[tid];                 // plain store
    if (tid == 0) pc[chunk] = (cw[0] + cw[1]) + (cw[2] + cw[3]);
}

__global__ __launch_bounds__(512) void gate_k(
    const float* __restrict__ w1f, const float* __restrict__ w2f,
    const float* __restrict__ w1t, const float* __restrict__ w2t,
    const float* __restrict__ w1c, const float* __restrict__ w2c,
    const float* __restrict__ pf, const float* __restrict__ pt,
    const float* __restrict__ pc, float* __restrict__ gates) {
    __shared__ __align__(16) float s[512];
    __shared__ __align__(16) float h[512];
    const int g = blockIdx.x >> 3;
    const int b = blockIdx.x & 7;
    const int tid = threadIdx.x;

    int dim; const float *w1, *w2; float* gout; float inv;
    if (g == 0) { dim = FF; w1 = w1f; w2 = w2f; gout = gates + b * FF;
                  inv = 1.f / (float)(CC * TT); }
    else if (g == 1) { dim = TT; w1 = w1t; w2 = w2t; gout = gates + TOFF + b * TT;
                  inv = 1.f / (float)(CC * FF); }
    else { dim = CC; w1 = w1c; w2 = w2c; gout = gates + COFF + b * CC;
                  inv = 1.f / (float)(TT * FF); }

    if (g == 0) {
        const int f = tid & 255, half = tid >> 8;
        float acc = 0.f;
        const float* __restrict__ p = pf + ((long)(b * 512 + half * 256) * 256) + f;
        #pragma unroll 8
        for (int ch = 0; ch < 256; ++ch) acc += p[(long)ch * 256];
        h[tid] = acc;
        __syncthreads();
        if (tid < 256) s[tid] = (h[tid] + h[tid + 256]) * inv;
    } else if (g == 1) {
        const int t = tid;
        float acc = 0.f;
        const float* __restrict__ p = pt + ((long)(b * 512 + (t >> 6)) * 64) + (t & 63);
        #pragma unroll 8
        for (int c = 0; c < 64; ++c) acc += p[(long)c * 8 * 64];
        s[t] = acc * inv;
    } else {
        if (tid < CC) {
            float acc = 0.f;
            #pragma unroll
            for (int j = 0; j < 8; ++j) acc += pc[b * 512 + tid * 8 + j];
            s[tid] = acc * inv;
        }
    }
    __syncthreads();

    for (int row = tid; row < dim; row += 512) {
        const floatx4* __restrict__ wr = (const floatx4*)(w1 + (long)row * dim);
        const floatx4* __restrict__ sv = (const floatx4*)s;
        float c0 = 0.f, c1 = 0.f, c2 = 0.f, c3 = 0.f;
        for (int j = 0; j < dim / 4; ++j) {
            floatx4 w = wr[j]; floatx4 sj = sv[j];
            c0 += w.x * sj.x; c1 += w.y * sj.y; c2 += w.z * sj.z; c3 += w.w * sj.w;
        }
        h[row] = fmaxf((c0 + c1) + (c2 + c3), 0.f);
    }
    __syncthreads();
    for (int row = tid; row < dim; row += 512) {
        const floatx4* __restrict__ wr = (const floatx4*)(w2 + (long)row * dim);
        const floatx4* __restrict__ hv = (const floatx4*)h;
        float c0 = 0.f, c1 = 0.f, c2 = 0.f, c3 = 0.f;
        for (int j = 0; j < dim / 4; ++j) {
            floatx4 w = wr[j]; floatx4 hj = hv[j];
            c0 += w.x * hj.x; c1 += w.y * hj.y; c2 += w.z * hj.z; c3 += w.w * hj.w;
        }
        gout[row] = 1.f / (1.f + expf(-((c0 + c1) + (c2 + c3))));
    }
}

__global__ __launch_bounds__(256) void apply_k(const float* __restrict__ x,
                                               const float* __restrict__ gts,
                                               float* __restrict__ out) {
    const floatx4* __restrict__ x4 = (const floatx4*)x;
    floatx4* __restrict__ o4 = (floatx4*)out;
    const long base3 = (long)blockIdx.x * 256 + threadIdx.x;   // < 2^19
    const int f4 = (int)(base3 & 63);
    const int t  = (int)((base3 >> 6) & (TT - 1));
    const int cb = (int)((base3 >> 15) & (CC - 1));
    #pragma unroll 8
    for (int k = 31; k >= 0; --k) {
        const int b = k >> 2;
        const int c = (cb + k * 16) & (CC - 1);
        const floatx4 fm = ((const floatx4*)(gts + b * FF))[f4];
        const float gadd = gts[TOFF + b * TT + t]
                         + gts[COFF + b * CC + c] + 1.0f;
        const long v = base3 + ((long)k << 19);
        floatx4 d = x4[v];                           // mostly L3 hits
        floatx4 o = d * (fm + gadd);
        __builtin_nontemporal_store(o, &o4[v]);
    }
}

extern "C" void kernel_launch(void* const* d_in, const int* in_sizes, int n_in,
                              void* d_out, int out_size, void* d_ws, size_t ws_size,
                              hipStream_t stream) {
    const float* x   = (const float*)d_in[0];
    const float* w1f = (const float*)d_in[1];
    const float* w2f = (const float*)d_in[2];
    const float* w1t = (const float*)d_in[3];
    const float* w2t = (const float*)d_in[4];
    const float* w1c = (const float*)d_in[5];
    const float* w2c = (const float*)d_in[6];
    float* out = (float*)d_out;

    float* ws    = (float*)d_ws;
    float* pf    = ws + PF_OFF;
    float* pt    = ws + PT_OFF;
    float* pc    = ws + PC_OFF;
    float* gates = ws + G_OFF;

    // R9 experiment: double pool and apply (idempotent) to measure their
    // marginal (hot) cost: R9 - R7 = pool_hot + apply_hot + 2 boundaries.
    pool_k<<<4096, 256, 0, stream>>>(x, pf, pt, pc);
    pool_k<<<4096, 256, 0, stream>>>(x, pf, pt, pc);
    gate_k<<<24, 512, 0, stream>>>(w1f, w2f, w1t, w2t, w1c, w2c,
                                   pf, pt, pc, gates);
    apply_k<<<2048, 256, 0, stream>>>(x, gates, out);
    apply_k<<<2048, 256, 0, stream>>>(x, gates, out);
}